// Round 5
// baseline (860.663 us; speedup 1.0000x reference)
//
#include <hip/hip_runtime.h>

#define DIMK 512
#define NBLK 64
#define NTOK 32768

typedef short  short8 __attribute__((ext_vector_type(8)));
typedef float  f32x4  __attribute__((ext_vector_type(4)));
typedef unsigned short u16x8 __attribute__((ext_vector_type(8)));

__device__ __forceinline__ unsigned short f2bf(float f) {
  union { float f; unsigned u; } v; v.f = f;
  unsigned r = (v.u + 0x7FFFu + ((v.u >> 16) & 1u)) >> 16;   // RNE
  return (unsigned short)r;
}
__device__ __forceinline__ float bf2f(unsigned short h) {
  return __uint_as_float(((unsigned)h) << 16);
}

// async 16B global -> LDS (wave-uniform base + lane*16)
__device__ __forceinline__ void gload_lds16(const unsigned short* g,
                                            unsigned short* l) {
  __builtin_amdgcn_global_load_lds(
      (const __attribute__((address_space(1))) unsigned int*)(g),
      (__attribute__((address_space(3))) unsigned int*)(l),
      16, 0, 0);
}

// ---------------------------------------------------------------------------
// K0: merged prep. id<8192: X fp32->bf16. id>=8192: Wt[w][n][k]=bf16(dw[k][n]).
// ---------------------------------------------------------------------------
__global__ __launch_bounds__(256) void k_prep(
    const float* __restrict__ X, const float* __restrict__ dw1,
    const float* __restrict__ dw2, const float* __restrict__ dw3,
    unsigned short* __restrict__ Xb, unsigned short* __restrict__ Wt)
{
  const int id = blockIdx.x;
  if (id < 8192) {
    const size_t i = ((size_t)id * 256 + threadIdx.x) * 8;
    const float4 a = *(const float4*)(X + i);
    const float4 b = *(const float4*)(X + i + 4);
    u16x8 o;
    o[0] = f2bf(a.x); o[1] = f2bf(a.y); o[2] = f2bf(a.z); o[3] = f2bf(a.w);
    o[4] = f2bf(b.x); o[5] = f2bf(b.y); o[6] = f2bf(b.z); o[7] = f2bf(b.w);
    *(u16x8*)(Xb + i) = o;
  } else {
    const int idx = (id - 8192) * 256 + threadIdx.x;   // < 786432
    const int w = idx >> 18;
    const int r = idx & 262143;
    const int n = r >> 9, k = r & 511;
    const float* dw = (w == 0) ? dw1 : (w == 1) ? dw2 : dw3;
    Wt[(size_t)w * 262144 + (size_t)n * 512 + k] = f2bf(dw[(size_t)k * 512 + n]);
  }
}

// ---------------------------------------------------------------------------
// K1: merged QKV. Block (mtile, nt): Q,K,V 128x128 tiles sharing one A-stage.
// Decode: x = id&7 (XCD), j = id>>3; mtile = x*32 + (j>>2), nt = j&3.
// LDS exactly 32 KB (As 8KB + Bs 24KB; V-transpose reuses 17.4KB in 2 passes).
// ---------------------------------------------------------------------------
__global__ __launch_bounds__(256, 4) void k_qkv(
    const unsigned short* __restrict__ Xb, const unsigned short* __restrict__ Wt,
    const float* __restrict__ db1, const float* __restrict__ db2,
    const float* __restrict__ db3,
    unsigned short* __restrict__ Qb, unsigned short* __restrict__ Kb,
    unsigned short* __restrict__ Vt)
{
  __shared__ __align__(16) unsigned short smem[16384];   // 32 KB
  unsigned short* As = smem;                             // 128x32
  unsigned short* Bs = smem + 4096;                      // 3 x 128x32

  const int id = blockIdx.x;
  const int x = id & 7, j = id >> 3;
  const int mtile = x * 32 + (j >> 2);
  const int nt = j & 3;
  const size_t m0 = (size_t)mtile * 128;
  const int n0 = nt * 128;

  const int tid = threadIdx.x, lane = tid & 63, wv = tid >> 6;
  const int quad = lane >> 4, l16 = lane & 15;
  const int rb = (wv >> 1) * 64, cb = (wv & 1) * 64;

  f32x4 acc[3][4][4];
#pragma unroll
  for (int w = 0; w < 3; ++w)
#pragma unroll
    for (int i = 0; i < 4; ++i)
#pragma unroll
      for (int jj = 0; jj < 4; ++jj) {
        f32x4 z = {0.f, 0.f, 0.f, 0.f}; acc[w][i][jj] = z;
      }

  const int ra0 = tid >> 2,          oa0 = (tid & 3) << 3;
  const int ra1 = (tid + 256) >> 2,  oa1 = ((tid + 256) & 3) << 3;
  const unsigned short* a0 = &Xb[(m0 + ra0) * (size_t)DIMK + oa0];
  const unsigned short* a1 = &Xb[(m0 + ra1) * (size_t)DIMK + oa1];

  for (int it = 0; it < 16; ++it) {
    const int k0 = it * 32;
    gload_lds16(a0 + k0, &As[tid * 8]);
    gload_lds16(a1 + k0, &As[(tid + 256) * 8]);
#pragma unroll
    for (int h = 0; h < 6; ++h) {
      const int c = tid + h * 256;          // 0..1535
      const int w = c >> 9, cc = c & 511;
      const int r = cc >> 2, o = (cc & 3) << 3;
      gload_lds16(&Wt[(size_t)w * 262144 + (size_t)(n0 + r) * 512 + k0 + o],
                  &Bs[w * 4096 + cc * 8]);
    }
    __syncthreads();
    short8 af[4];
#pragma unroll
    for (int i = 0; i < 4; ++i)
      af[i] = *(const short8*)&As[(rb + i * 16 + l16) * 32 + quad * 8];
#pragma unroll
    for (int jj = 0; jj < 4; ++jj)
#pragma unroll
      for (int w = 0; w < 3; ++w) {
        const short8 bf =
            *(const short8*)&Bs[w * 4096 + (cb + jj * 16 + l16) * 32 + quad * 8];
#pragma unroll
        for (int i = 0; i < 4; ++i)
          acc[w][i][jj] = __builtin_amdgcn_mfma_f32_16x16x32_bf16(
              af[i], bf, acc[w][i][jj], 0, 0, 0);
      }
    __syncthreads();
  }

  // ---- Q, K direct stores ----
#pragma unroll
  for (int w = 0; w < 2; ++w) {
    const float* db = (w == 0) ? db1 : db2;
    unsigned short* Ob = (w == 0) ? Qb : Kb;
#pragma unroll
    for (int i = 0; i < 4; ++i)
#pragma unroll
      for (int jj = 0; jj < 4; ++jj)
#pragma unroll
        for (int r = 0; r < 4; ++r) {
          const size_t row = m0 + rb + i * 16 + quad * 4 + r;
          const int col = n0 + cb + jj * 16 + l16;
          Ob[row * (size_t)DIMK + col] = f2bf(acc[w][i][jj][r] + db[col]);
        }
  }

  // ---- V: 2-pass LDS transpose (64 cols x 128 toks, stride 136) ----
  const int blk = mtile >> 2;
  const int tokbase = (mtile & 3) * 128;
  unsigned short* Vblk = Vt + (size_t)blk * 262144;
#pragma unroll
  for (int pass = 0; pass < 2; ++pass) {
    if (pass) __syncthreads();              // previous copy done
    if ((wv & 1) == pass) {
#pragma unroll
      for (int i = 0; i < 4; ++i)
#pragma unroll
        for (int jj = 0; jj < 4; ++jj) {
          const int cl = jj * 16 + l16;            // 0..63 within pass
          const int t0 = rb + i * 16 + quad * 4;   // 0..127
          const float bv = db3[n0 + pass * 64 + cl];
          ushort4 pk;
          pk.x = f2bf(acc[2][i][jj][0] + bv);
          pk.y = f2bf(acc[2][i][jj][1] + bv);
          pk.z = f2bf(acc[2][i][jj][2] + bv);
          pk.w = f2bf(acc[2][i][jj][3] + bv);
          *(ushort4*)&smem[cl * 136 + t0] = pk;
        }
    }
    __syncthreads();
#pragma unroll
    for (int h = 0; h < 4; ++h) {
      const int c = tid + h * 256;                 // 0..1023 16B chunks
      const int cl = c >> 4, toff = (c & 15) * 8;
      *(u16x8*)&Vblk[(size_t)(n0 + pass * 64 + cl) * 512 + tokbase + toff] =
          *(const u16x8*)&smem[cl * 136 + toff];
    }
  }
}

// ---------------------------------------------------------------------------
// K2: FUSED attention: S=QK^T/sqrt(512)+mask, softmax, P·V + residual + LN.
// Block = 64 queries x 512 keys. P lives in LDS (never global).
// Flat grid 512: blk = id & 63 (XCD-coherent), mt = id >> 6.
// ---------------------------------------------------------------------------
__global__ __launch_bounds__(256, 1) void k_attn(
    const unsigned short* __restrict__ Qb, const unsigned short* __restrict__ Kb,
    const unsigned short* __restrict__ Vt, const float* __restrict__ mask,
    const unsigned short* __restrict__ Xb, float* __restrict__ Out)
{
  __shared__ __align__(16) unsigned short Pl[64 * 520];   // 66.6 KB
  __shared__ __align__(16) unsigned short As[64 * 32];    // 4 KB (Q stage)
  __shared__ __align__(16) unsigned short Bs[512 * 32];   // 32 KB (K / Vt)
  __shared__ float  redA[4][64];
  __shared__ float2 redB[4][64];

  const int tid = threadIdx.x, lane = tid & 63, wv = tid >> 6;
  const int quad = lane >> 4, l16 = lane & 15;
  const int blk = blockIdx.x & 63, mt = blockIdx.x >> 6;
  const size_t tb = (size_t)blk * 512;
  const size_t q0 = tb + (size_t)mt * 64;

  f32x4 acc[4][8];
#pragma unroll
  for (int i = 0; i < 4; ++i)
#pragma unroll
    for (int j = 0; j < 8; ++j) { f32x4 z = {0.f, 0.f, 0.f, 0.f}; acc[i][j] = z; }

  const int ra = tid >> 2, oa = (tid & 3) << 3;
  const unsigned short* ap = &Qb[(q0 + ra) * (size_t)DIMK + oa];
  const unsigned short* kp = &Kb[tb * (size_t)DIMK];

  // ---------- phase 1: S = Q K^T ----------
  for (int it = 0; it < 16; ++it) {
    const int k0 = it * 32;
    gload_lds16(ap + k0, &As[tid * 8]);
#pragma unroll
    for (int h = 0; h < 8; ++h) {
      const int c = tid + h * 256;
      const int r = c >> 2, o = (c & 3) << 3;
      gload_lds16(kp + (size_t)r * DIMK + k0 + o, &Bs[c * 8]);
    }
    __syncthreads();
    short8 af[4], bfv[8];
#pragma unroll
    for (int i = 0; i < 4; ++i)
      af[i] = *(const short8*)&As[(i * 16 + l16) * 32 + quad * 8];
#pragma unroll
    for (int j = 0; j < 8; ++j)
      bfv[j] = *(const short8*)&Bs[(wv * 128 + j * 16 + l16) * 32 + quad * 8];
#pragma unroll
    for (int i = 0; i < 4; ++i)
#pragma unroll
      for (int j = 0; j < 8; ++j)
        acc[i][j] = __builtin_amdgcn_mfma_f32_16x16x32_bf16(
            af[i], bfv[j], acc[i][j], 0, 0, 0);
    __syncthreads();
  }

  // ---------- mask + softmax ----------
  const float scale = 0.04419417382415922f;   // 1/sqrt(512)
  float rmax[4][4];
#pragma unroll
  for (int i = 0; i < 4; ++i)
#pragma unroll
    for (int r = 0; r < 4; ++r) rmax[i][r] = -3.0e38f;
#pragma unroll
  for (int i = 0; i < 4; ++i)
#pragma unroll
    for (int j = 0; j < 8; ++j)
#pragma unroll
      for (int r = 0; r < 4; ++r) {
        const size_t tok = q0 + i * 16 + quad * 4 + r;
        const int col = wv * 128 + j * 16 + l16;
        const float m = mask[tok * (size_t)DIMK + col];
        const float v = acc[i][j][r] * scale + (1.0f - m) * (-1e10f);
        acc[i][j][r] = v;
        rmax[i][r] = fmaxf(rmax[i][r], v);
      }
#pragma unroll
  for (int i = 0; i < 4; ++i)
#pragma unroll
    for (int r = 0; r < 4; ++r)
      for (int d = 1; d < 16; d <<= 1)
        rmax[i][r] = fmaxf(rmax[i][r], __shfl_xor(rmax[i][r], d, 64));
  if (l16 == 0)
#pragma unroll
    for (int i = 0; i < 4; ++i)
#pragma unroll
      for (int r = 0; r < 4; ++r) redA[wv][i * 16 + quad * 4 + r] = rmax[i][r];
  __syncthreads();
#pragma unroll
  for (int i = 0; i < 4; ++i)
#pragma unroll
    for (int r = 0; r < 4; ++r) {
      const int row = i * 16 + quad * 4 + r;
      rmax[i][r] = fmaxf(fmaxf(redA[0][row], redA[1][row]),
                         fmaxf(redA[2][row], redA[3][row]));
    }
  __syncthreads();
  float rsum[4][4];
#pragma unroll
  for (int i = 0; i < 4; ++i)
#pragma unroll
    for (int r = 0; r < 4; ++r) rsum[i][r] = 0.f;
#pragma unroll
  for (int i = 0; i < 4; ++i)
#pragma unroll
    for (int j = 0; j < 8; ++j)
#pragma unroll
      for (int r = 0; r < 4; ++r) {
        const float e = __expf(acc[i][j][r] - rmax[i][r]);
        acc[i][j][r] = e;
        rsum[i][r] += e;
      }
#pragma unroll
  for (int i = 0; i < 4; ++i)
#pragma unroll
    for (int r = 0; r < 4; ++r)
      for (int d = 1; d < 16; d <<= 1)
        rsum[i][r] += __shfl_xor(rsum[i][r], d, 64);
  if (l16 == 0)
#pragma unroll
    for (int i = 0; i < 4; ++i)
#pragma unroll
      for (int r = 0; r < 4; ++r) redA[wv][i * 16 + quad * 4 + r] = rsum[i][r];
  __syncthreads();
#pragma unroll
  for (int i = 0; i < 4; ++i)
#pragma unroll
    for (int r = 0; r < 4; ++r) {
      const int row = i * 16 + quad * 4 + r;
      rsum[i][r] = 1.0f / (redA[0][row] + redA[1][row] +
                           redA[2][row] + redA[3][row]);
    }
  // write P (bf16) to LDS: Pl[q][key], stride 520 (16B-aligned rows)
#pragma unroll
  for (int i = 0; i < 4; ++i)
#pragma unroll
    for (int j = 0; j < 8; ++j)
#pragma unroll
      for (int r = 0; r < 4; ++r) {
        const int q = i * 16 + quad * 4 + r;
        const int key = wv * 128 + j * 16 + l16;
        Pl[q * 520 + key] = f2bf(acc[i][j][r] * rsum[i][r]);
      }
  __syncthreads();

  // ---------- phase 2: Out = P V (+res, LN) ----------
#pragma unroll
  for (int i = 0; i < 4; ++i)
#pragma unroll
    for (int j = 0; j < 8; ++j) { f32x4 z = {0.f, 0.f, 0.f, 0.f}; acc[i][j] = z; }

  const unsigned short* vp = Vt + (size_t)blk * 262144;   // [d][tok]
  for (int it = 0; it < 16; ++it) {
    const int k0 = it * 32;
#pragma unroll
    for (int h = 0; h < 8; ++h) {
      const int c = tid + h * 256;
      const int r = c >> 2, o = (c & 3) << 3;
      gload_lds16(vp + (size_t)r * DIMK + k0 + o, &Bs[c * 8]);
    }
    __syncthreads();
    short8 af[4], bfv[8];
#pragma unroll
    for (int i = 0; i < 4; ++i)
      af[i] = *(const short8*)&Pl[(i * 16 + l16) * 520 + k0 + quad * 8];
#pragma unroll
    for (int j = 0; j < 8; ++j)
      bfv[j] = *(const short8*)&Bs[(wv * 128 + j * 16 + l16) * 32 + quad * 8];
#pragma unroll
    for (int i = 0; i < 4; ++i)
#pragma unroll
      for (int j = 0; j < 8; ++j)
        acc[i][j] = __builtin_amdgcn_mfma_f32_16x16x32_bf16(
            af[i], bfv[j], acc[i][j], 0, 0, 0);
    __syncthreads();
  }

  // ---------- residual + LayerNorm ----------
  float vsum[4][4], vsq[4][4];
#pragma unroll
  for (int i = 0; i < 4; ++i)
#pragma unroll
    for (int r = 0; r < 4; ++r) { vsum[i][r] = 0.f; vsq[i][r] = 0.f; }
#pragma unroll
  for (int i = 0; i < 4; ++i)
#pragma unroll
    for (int j = 0; j < 8; ++j)
#pragma unroll
      for (int r = 0; r < 4; ++r) {
        const size_t tok = q0 + i * 16 + quad * 4 + r;
        const int col = wv * 128 + j * 16 + l16;
        const float v = acc[i][j][r] + bf2f(Xb[tok * (size_t)DIMK + col]);
        acc[i][j][r] = v;
        vsum[i][r] += v;
        vsq[i][r] += v * v;
      }
#pragma unroll
  for (int i = 0; i < 4; ++i)
#pragma unroll
    for (int r = 0; r < 4; ++r)
      for (int d = 1; d < 16; d <<= 1) {
        vsum[i][r] += __shfl_xor(vsum[i][r], d, 64);
        vsq[i][r]  += __shfl_xor(vsq[i][r], d, 64);
      }
  if (l16 == 0)
#pragma unroll
    for (int i = 0; i < 4; ++i)
#pragma unroll
      for (int r = 0; r < 4; ++r) {
        float2 p; p.x = vsum[i][r]; p.y = vsq[i][r];
        redB[wv][i * 16 + quad * 4 + r] = p;
      }
  __syncthreads();
#pragma unroll
  for (int i = 0; i < 4; ++i)
#pragma unroll
    for (int r = 0; r < 4; ++r) {
      const int row = i * 16 + quad * 4 + r;
      float s = 0.f, q = 0.f;
#pragma unroll
      for (int w = 0; w < 4; ++w) { s += redB[w][row].x; q += redB[w][row].y; }
      const float mean = s * (1.0f / 512.0f);
      const float var  = q * (1.0f / 512.0f) - mean * mean;
      vsum[i][r] = mean;
      vsq[i][r]  = rsqrtf(var + 1e-3f);
    }
#pragma unroll
  for (int i = 0; i < 4; ++i)
#pragma unroll
    for (int j = 0; j < 8; ++j)
#pragma unroll
      for (int r = 0; r < 4; ++r) {
        const size_t tok = q0 + i * 16 + quad * 4 + r;
        const int col = wv * 128 + j * 16 + l16;
        Out[tok * (size_t)DIMK + col] =
            (acc[i][j][r] - vsum[i][r]) * vsq[i][r];
      }
}

// ---------------------------------------------------------------------------
extern "C" void kernel_launch(void* const* d_in, const int* in_sizes, int n_in,
                              void* d_out, int out_size, void* d_ws, size_t ws_size,
                              hipStream_t stream)
{
  const float* X    = (const float*)d_in[0];
  const float* mask = (const float*)d_in[1];
  const float* dw1  = (const float*)d_in[2];
  const float* dw2  = (const float*)d_in[3];
  const float* dw3  = (const float*)d_in[4];
  const float* db1  = (const float*)d_in[5];
  const float* db2  = (const float*)d_in[6];
  const float* db3  = (const float*)d_in[7];
  float* Out = (float*)d_out;

  char* ws = (char*)d_ws;
  const size_t MB = 1ull << 20;
  // ws (130 MB): [Wt 2 | Qb 32 | Kb 32 | Vt 32 | Xb 32]
  unsigned short* Wt = (unsigned short*)(ws);
  unsigned short* Qb = (unsigned short*)(ws + 2 * MB);
  unsigned short* Kb = (unsigned short*)(ws + 34 * MB);
  unsigned short* Vt = (unsigned short*)(ws + 66 * MB);
  unsigned short* Xb = (unsigned short*)(ws + 98 * MB);

  k_prep<<<11264, 256, 0, stream>>>(X, dw1, dw2, dw3, Xb, Wt);
  k_qkv <<<1024, 256, 0, stream>>>(Xb, Wt, db1, db2, db3, Qb, Kb, Vt);
  k_attn<<<512, 256, 0, stream>>>(Qb, Kb, Vt, mask, Xb, Out);
}